// Round 8
// baseline (43.894 us; speedup 1.0000x reference)
//
#include <hip/hip_runtime.h>
#include <hip/hip_bf16.h>
#include <math.h>

#define N_CELLS 8192
#define D_DIM 64
#define H_DIM 128
#define GRID_SZ 256
#define NBINS (GRID_SZ * GRID_SZ)
#define BUCKET_CAP 16

typedef short bf16x8 __attribute__((ext_vector_type(8)));
typedef float f32x4 __attribute__((ext_vector_type(4)));

static __device__ __forceinline__ short f2bf(float x) {
    __hip_bfloat16 b = __float2bfloat16(x);
    return __builtin_bit_cast(short, b);
}

// ---------------- K1: prep — Wb pack (0..127) | clear counts (128..191) |
//                  W_out hi/lo pack transposed (192..223) | W_role pad (224) ----------------
__global__ __launch_bounds__(256) void prep(const float* __restrict__ Wih,
                                            const float* __restrict__ Whh,
                                            const float* __restrict__ W_out,
                                            const float* __restrict__ W_role,
                                            __hip_bfloat16* __restrict__ Wb,
                                            __hip_bfloat16* __restrict__ Wohi,
                                            __hip_bfloat16* __restrict__ Wolo,
                                            __hip_bfloat16* __restrict__ Wr,
                                            int4* __restrict__ counts4) {
    int tid = threadIdx.x, b = blockIdx.x;
    if (b < 128) {
        // Wb row g': group=g'>>6, c6=g'&63, gate=c6>>4, hl=c6&15; orig = gate*128+group*16+hl
        int idx4 = b * 256 + tid;   // 32768 float4 chunks
        int gp = idx4 >> 6, k4 = (idx4 & 63) << 2;
        int group = gp >> 6, c6 = gp & 63, gate = c6 >> 4, hl = c6 & 15;
        int orig = gate * 128 + group * 16 + hl;
        float4 v = (k4 < 128) ? *(const float4*)(Wih + orig * 128 + k4)
                              : *(const float4*)(Whh + orig * 128 + (k4 - 128));
        short4 o = make_short4(f2bf(v.x), f2bf(v.y), f2bf(v.z), f2bf(v.w));
        *(short4*)((short*)Wb + gp * 256 + k4) = o;
    } else if (b < 192) {
        counts4[(b - 128) * 256 + tid] = make_int4(0, 0, 0, 0);
    } else if (b < 224) {
        int u = (b - 192) * 256 + tid;       // 8192: u = h*64 + d
        int hh = u >> 6, d = u & 63;
        float w = W_out[u];
        float whi = __bfloat162float(__float2bfloat16(w));
        Wohi[d * 128 + hh] = __float2bfloat16(whi);
        Wolo[d * 128 + hh] = __float2bfloat16(w - whi);
    } else {
        #pragma unroll
        for (int e = 0; e < 8; ++e) {        // 2048: r(16) x h(128), rows 3..15 zero
            int u = e * 256 + tid;
            int r = u >> 7, hh = u & 127;
            float w = (r < 3) ? W_role[hh * 3 + r] : 0.0f;
            Wr[r * 128 + hh] = __float2bfloat16(w);
        }
    }
}

// ---------------- K2: fill spatial-hash buckets ----------------
__global__ __launch_bounds__(256) void bin_fill(const int* __restrict__ positions,
                                                int* __restrict__ counts,
                                                int* __restrict__ buckets) {
    int i = blockIdx.x * 256 + threadIdx.x;
    if (i >= N_CELLS) return;
    int p0 = positions[2 * i], p1 = positions[2 * i + 1];
    int bin = p0 * GRID_SZ + p1;
    int slot = atomicAdd(&counts[bin], 1);
    if (slot < BUCKET_CAP) buckets[bin * BUCKET_CAP + slot] = i;
}

// ---------------- K3: neighbor mean + xh(bf16) assembly — one wave per cell ----------------
__global__ __launch_bounds__(256) void build_xh(const int* __restrict__ positions,
                                                const float* __restrict__ states,
                                                const float* __restrict__ h,
                                                const int* __restrict__ counts,
                                                const int* __restrict__ buckets,
                                                __hip_bfloat16* __restrict__ xh) {
    int wave = threadIdx.x >> 6;
    int lane = threadIdx.x & 63;
    int i = blockIdx.x * 4 + wave;
    int p0 = positions[2 * i], p1 = positions[2 * i + 1];

    float acc = 0.0f;
    int cnt = 0;
    #pragma unroll
    for (int da = -3; da <= 3; ++da) {
        int q0 = p0 + da;
        if (q0 < 0 || q0 >= GRID_SZ) continue;
        int maxdb2 = 9 - da * da;
        #pragma unroll
        for (int db = -3; db <= 3; ++db) {
            if (db * db > maxdb2) continue;
            int q1 = p1 + db;
            if (q1 < 0 || q1 >= GRID_SZ) continue;
            int bin = q0 * GRID_SZ + q1;
            int c = counts[bin];
            if (c > BUCKET_CAP) c = BUCKET_CAP;
            for (int s = 0; s < c; ++s) {
                int j = buckets[bin * BUCKET_CAP + s];
                if (j == i) continue;   // exclude self (same-position others DO count)
                cnt++;
                acc += states[j * D_DIM + lane];
            }
        }
    }
    float nbr = (cnt > 0) ? acc / (float)cnt : 0.0f;

    __hip_bfloat16* row = xh + (size_t)i * 256;
    row[lane]       = __float2bfloat16(states[i * D_DIM + lane]);
    row[64 + lane]  = __float2bfloat16(nbr);
    row[128 + lane] = __float2bfloat16(h[i * H_DIM + lane]);
    row[192 + lane] = __float2bfloat16(h[i * H_DIM + 64 + lane]);
}

// ---------------- K4: mega1 — gate GEMM (BM=32, BN=256) + LSTM -> h_new (bf16) ----------------
// 512 blocks x 256 thr (4 waves, 2x2). A-fragments direct global->reg; B via 32KB LDS (swizzled).
__global__ __launch_bounds__(256) void mega1(const __hip_bfloat16* __restrict__ xh,
                                             const __hip_bfloat16* __restrict__ Wb,
                                             const float* __restrict__ bias,
                                             const float* __restrict__ c_in,
                                             __hip_bfloat16* __restrict__ h_new) {
    __shared__ char Bs[32768];             // 256 rows x 128B per kc chunk

    const int tid  = threadIdx.x;
    const int lane = tid & 63;
    const int wid  = tid >> 6;
    const int wrow = wid >> 1, wcol = wid & 1;
    const int nb = blockIdx.x >> 1, gb = blockIdx.x & 1;
    const int n0 = nb * 32, g0 = gb * 256;

    // A fragments: rows n0+wrow*16+(lane&15), k = z*32 + (lane>>4)*8  (z = kc*2+ks)
    const short* xr = (const short*)xh + (size_t)(n0 + wrow * 16 + (lane & 15)) * 256 + ((lane >> 4) << 3);
    bf16x8 av[8];
    #pragma unroll
    for (int z = 0; z < 8; ++z) av[z] = *(const bf16x8*)(xr + z * 32);

    // c_in prefetch (T14): wave's h-groups = gb*4 + 2*wcol + b
    float cv[2][4];
    #pragma unroll
    for (int b = 0; b < 2; ++b) {
        int hg = (gb * 4 + 2 * wcol + b) * 16 + (lane & 15);
        #pragma unroll
        for (int r = 0; r < 4; ++r) {
            int ml = wrow * 16 + ((lane >> 4) << 2) + r;
            cv[b][r] = c_in[(size_t)(n0 + ml) * H_DIM + hg];
        }
    }

    const char* bG = (const char*)Wb;      // row stride 512B
    f32x4 acc[8] = {};

    for (int kc = 0; kc < 4; ++kc) {
        if (kc) __syncthreads();
        #pragma unroll
        for (int e = 0; e < 8; ++e) {      // stage Bs: 2048 x 16B
            int u = e * 256 + tid;
            int row = u >> 3, slot = (u & 7) << 4;
            __builtin_amdgcn_global_load_lds(
                (const __attribute__((address_space(1))) void*)(bG + (size_t)(g0 + row) * 512 + kc * 128 + (slot ^ ((row & 7) << 4))),
                (__attribute__((address_space(3))) void*)(Bs + row * 128 + slot), 16, 0, 0);
        }
        __syncthreads();

        #pragma unroll
        for (int ks = 0; ks < 2; ++ks) {
            int kb = ks * 64 + ((lane >> 4) << 4);
            #pragma unroll
            for (int ni = 0; ni < 8; ++ni) {
                int brow = wcol * 128 + ni * 16 + (lane & 15);
                bf16x8 bv = *(const bf16x8*)(Bs + brow * 128 + (kb ^ ((brow & 7) << 4)));
                acc[ni] = __builtin_amdgcn_mfma_f32_16x16x32_bf16(av[kc * 2 + ks], bv, acc[ni], 0, 0, 0);
            }
        }
    }

    // LSTM pointwise; acc layout: ni = b*4 + gate (gate-interleaved Wb), col h = group*16+(lane&15)
    #pragma unroll
    for (int b = 0; b < 2; ++b) {
        int hg = (gb * 4 + 2 * wcol + b) * 16 + (lane & 15);
        float bi = bias[hg], bff = bias[128 + hg], bgg = bias[256 + hg], boo = bias[384 + hg];
        #pragma unroll
        for (int r = 0; r < 4; ++r) {
            int ml = wrow * 16 + ((lane >> 4) << 2) + r;
            float ig = acc[b * 4 + 0][r] + bi;
            float fg = acc[b * 4 + 1][r] + bff;
            float gg = acc[b * 4 + 2][r] + bgg;
            float og = acc[b * 4 + 3][r] + boo;
            float si = 1.0f / (1.0f + expf(-ig));
            float sf = 1.0f / (1.0f + expf(-fg));
            float so = 1.0f / (1.0f + expf(-og));
            float hn = so * tanhf(sf * cv[b][r] + si * tanhf(gg));
            h_new[(size_t)(n0 + ml) * H_DIM + hg] = __float2bfloat16(hn);
        }
    }
}

// ---------------- K5: mega2 — heads: out = h @ W_out(hi+lo), role softmax ----------------
// 512 blocks x 256 thr (BM=16). h direct global->reg; W staged via LDS (36KB, swizzled).
__global__ __launch_bounds__(256) void mega2(const __hip_bfloat16* __restrict__ h_new,
                                             const __hip_bfloat16* __restrict__ Wohi,
                                             const __hip_bfloat16* __restrict__ Wolo,
                                             const __hip_bfloat16* __restrict__ Wr,
                                             float* __restrict__ out) {
    __shared__ char smem[36864];           // Whi 16KB @0 | Wlo 16KB @16384 | Wr 4KB @32768

    const int tid  = threadIdx.x;
    const int lane = tid & 63;
    const int w    = tid >> 6;             // wave = d-block 0..3
    const int n0   = blockIdx.x * 16;

    const char* hiG = (const char*)Wohi;   // [64][128] bf16, row 256B
    const char* loG = (const char*)Wolo;
    const char* wrG = (const char*)Wr;     // [16][128] bf16

    #pragma unroll
    for (int e = 0; e < 4; ++e) {          // Whi: 1024 x 16B
        int u = e * 256 + tid;
        int row = u >> 4, slot = (u & 15) << 4;
        __builtin_amdgcn_global_load_lds(
            (const __attribute__((address_space(1))) void*)(hiG + row * 256 + (slot ^ ((row & 7) << 4))),
            (__attribute__((address_space(3))) void*)(smem + row * 256 + slot), 16, 0, 0);
    }
    #pragma unroll
    for (int e = 0; e < 4; ++e) {          // Wlo
        int u = e * 256 + tid;
        int row = u >> 4, slot = (u & 15) << 4;
        __builtin_amdgcn_global_load_lds(
            (const __attribute__((address_space(1))) void*)(loG + row * 256 + (slot ^ ((row & 7) << 4))),
            (__attribute__((address_space(3))) void*)(smem + 16384 + row * 256 + slot), 16, 0, 0);
    }
    {                                       // Wr: 256 x 16B
        int row = tid >> 4, slot = (tid & 15) << 4;
        __builtin_amdgcn_global_load_lds(
            (const __attribute__((address_space(1))) void*)(wrG + row * 256 + (slot ^ ((row & 7) << 4))),
            (__attribute__((address_space(3))) void*)(smem + 32768 + row * 256 + slot), 16, 0, 0);
    }

    // h fragments direct: rows n0+(lane&15), k = ks*32 + (lane>>4)*8
    const short* hr = (const short*)h_new + (size_t)(n0 + (lane & 15)) * H_DIM + ((lane >> 4) << 3);
    bf16x8 hv[4];
    #pragma unroll
    for (int ks = 0; ks < 4; ++ks) hv[ks] = *(const bf16x8*)(hr + ks * 32);

    __syncthreads();

    f32x4 oacc = {};
    f32x4 racc = {};
    #pragma unroll
    for (int ks = 0; ks < 4; ++ks) {
        int kb = ks * 64 + ((lane >> 4) << 4);
        int drow = w * 16 + (lane & 15);
        int woff = drow * 256 + (kb ^ ((drow & 7) << 4));
        bf16x8 whi = *(const bf16x8*)(smem + woff);
        bf16x8 wlo = *(const bf16x8*)(smem + 16384 + woff);
        oacc = __builtin_amdgcn_mfma_f32_16x16x32_bf16(hv[ks], whi, oacc, 0, 0, 0);
        oacc = __builtin_amdgcn_mfma_f32_16x16x32_bf16(hv[ks], wlo, oacc, 0, 0, 0);
        if (w == 0) {
            int rrow = lane & 15;
            bf16x8 wr = *(const bf16x8*)(smem + 32768 + rrow * 256 + (kb ^ ((rrow & 7) << 4)));
            racc = __builtin_amdgcn_mfma_f32_16x16x32_bf16(wr, hv[ks], racc, 0, 0, 0);
        }
    }
    #pragma unroll
    for (int r = 0; r < 4; ++r) {
        int m = n0 + ((lane >> 4) << 2) + r;
        out[(size_t)m * D_DIM + w * 16 + (lane & 15)] = oacc[r];
    }
    if (w == 0 && lane < 16) {
        int m = n0 + lane;
        float l0 = racc[0], l1 = racc[1], l2 = racc[2];
        float mx = fmaxf(l0, fmaxf(l1, l2));
        float e0 = expf(l0 - mx), e1 = expf(l1 - mx), e2 = expf(l2 - mx);
        float s = e0 + e1 + e2;
        float* ro = out + (size_t)N_CELLS * D_DIM + (size_t)m * 3;
        ro[0] = e0 / s; ro[1] = e1 / s; ro[2] = e2 / s;
    }
}

// ---------------- host launcher ----------------
extern "C" void kernel_launch(void* const* d_in, const int* in_sizes, int n_in,
                              void* d_out, int out_size, void* d_ws, size_t ws_size,
                              hipStream_t stream) {
    const int*   positions = (const int*)d_in[0];
    const float* states    = (const float*)d_in[1];
    const float* h         = (const float*)d_in[2];
    const float* c         = (const float*)d_in[3];
    const float* Wih       = (const float*)d_in[4];
    const float* Whh       = (const float*)d_in[5];
    const float* bias      = (const float*)d_in[6];
    const float* Wout      = (const float*)d_in[7];
    const float* Wrole     = (const float*)d_in[8];
    float* out             = (float*)d_out;

    char* ws = (char*)d_ws;
    int*            counts  = (int*)ws;                          // 256 KB @ 0
    int*            buckets = (int*)(ws + 262144);               // 4 MB
    __hip_bfloat16* xh      = (__hip_bfloat16*)(ws + 4456448);   // 4 MB   [8192,256] bf16
    __hip_bfloat16* Wb      = (__hip_bfloat16*)(ws + 8650752);   // 256 KB [512,256] bf16
    __hip_bfloat16* Wohi    = (__hip_bfloat16*)(ws + 8912896);   // 16 KB  [64,128] bf16
    __hip_bfloat16* Wolo    = (__hip_bfloat16*)(ws + 8929280);   // 16 KB
    __hip_bfloat16* Wr      = (__hip_bfloat16*)(ws + 8945664);   // 4 KB   [16,128] bf16
    __hip_bfloat16* h_new   = (__hip_bfloat16*)(ws + 8949760);   // 2 MB   [8192,128] bf16

    prep<<<225, 256, 0, stream>>>(Wih, Whh, Wout, Wrole, Wb, Wohi, Wolo, Wr, (int4*)counts);
    bin_fill<<<N_CELLS / 256, 256, 0, stream>>>(positions, counts, buckets);
    build_xh<<<N_CELLS / 4, 256, 0, stream>>>(positions, states, h, counts, buckets, xh);
    mega1<<<512, 256, 0, stream>>>(xh, Wb, bias, c, h_new);
    mega2<<<512, 256, 0, stream>>>(h_new, Wohi, Wolo, Wr, out);
}

// Round 9
// 34.591 us; speedup vs baseline: 1.2690x; 1.2690x over previous
//
#include <hip/hip_runtime.h>
#include <hip/hip_bf16.h>
#include <math.h>

#define N_CELLS 8192
#define D_DIM 64
#define H_DIM 128
#define GRID_SZ 256
#define NBINS (GRID_SZ * GRID_SZ)
#define BUCKET_CAP 16

typedef short bf16x8 __attribute__((ext_vector_type(8)));
typedef float f32x4 __attribute__((ext_vector_type(4)));

static __device__ __forceinline__ short f2bf(float x) {
    __hip_bfloat16 b = __float2bfloat16(x);
    return __builtin_bit_cast(short, b);
}

// ---------------- K1: prep — Wb pack/permute (blocks 0..127) + clear counts (128..191) ----
__global__ __launch_bounds__(256) void prep(const float* __restrict__ Wih,
                                            const float* __restrict__ Whh,
                                            __hip_bfloat16* __restrict__ Wb,
                                            int4* __restrict__ counts4) {
    int tid = threadIdx.x, b = blockIdx.x;
    if (b >= 128) {
        counts4[(b - 128) * 256 + tid] = make_int4(0, 0, 0, 0);
        return;
    }
    // Wb row g': group=g'>>6, c6=g'&63, gate=c6>>4, hl=c6&15; orig = gate*128+group*16+hl
    int idx4 = b * 256 + tid;   // 32768 float4 chunks
    int gp = idx4 >> 6, k4 = (idx4 & 63) << 2;
    int group = gp >> 6, c6 = gp & 63, gate = c6 >> 4, hl = c6 & 15;
    int orig = gate * 128 + group * 16 + hl;
    float4 v = (k4 < 128) ? *(const float4*)(Wih + orig * 128 + k4)
                          : *(const float4*)(Whh + orig * 128 + (k4 - 128));
    short4 o = make_short4(f2bf(v.x), f2bf(v.y), f2bf(v.z), f2bf(v.w));
    *(short4*)((short*)Wb + gp * 256 + k4) = o;
}

// ---------------- K2: fill spatial-hash buckets ----------------
__global__ __launch_bounds__(256) void bin_fill(const int* __restrict__ positions,
                                                int* __restrict__ counts,
                                                int* __restrict__ buckets) {
    int i = blockIdx.x * 256 + threadIdx.x;
    if (i >= N_CELLS) return;
    int p0 = positions[2 * i], p1 = positions[2 * i + 1];
    int bin = p0 * GRID_SZ + p1;
    int slot = atomicAdd(&counts[bin], 1);
    if (slot < BUCKET_CAP) buckets[bin * BUCKET_CAP + slot] = i;
}

// ---------------- K3: build_xh — WAVE-PARALLEL gather (lane t probes stencil bin t) ----------
// Chain: positions -> {counts || bucket int4} in parallel -> ballot scan -> states loads.
__global__ __launch_bounds__(256) void build_xh(const int* __restrict__ positions,
                                                const float* __restrict__ states,
                                                const float* __restrict__ h,
                                                const int* __restrict__ counts,
                                                const int* __restrict__ buckets,
                                                __hip_bfloat16* __restrict__ xh) {
    int wave = threadIdx.x >> 6;
    int lane = threadIdx.x & 63;
    int i = blockIdx.x * 4 + wave;   // one wave per cell
    int p0 = positions[2 * i], p1 = positions[2 * i + 1];

    // lane t -> stencil offset (da,db), t in [0,29); enumeration matches da-major, db-minor order
    int t = lane;
    int da, db;
    if (t == 0)      { da = -3; db = 0; }
    else if (t < 6)  { da = -2; db = t - 3; }
    else if (t < 11) { da = -1; db = t - 8; }
    else if (t < 18) { da = 0;  db = t - 14; }
    else if (t < 23) { da = 1;  db = t - 20; }
    else if (t < 28) { da = 2;  db = t - 25; }
    else             { da = 3;  db = 0; }

    int q0 = p0 + da, q1 = p1 + db;
    bool ok = (lane < 29) && ((unsigned)q0 < GRID_SZ) && ((unsigned)q1 < GRID_SZ);
    int bin = q0 * GRID_SZ + q1;

    int cl = 0;
    int4 jv = make_int4(0, 0, 0, 0);
    if (ok) {
        cl = counts[bin];                             // parallel across lanes
        jv = *(const int4*)(buckets + bin * BUCKET_CAP);  // independent of cl -> same latency wave
        if (cl > BUCKET_CAP) cl = BUCKET_CAP;
    }

    unsigned long long act = __ballot(cl > 0);
    float acc = 0.0f;
    int cnt = 0;
    while (act) {
        int tb = __ffsll(act) - 1;
        act &= act - 1;
        int ct = __shfl(cl, tb);
        int j0 = __shfl(jv.x, tb), j1 = __shfl(jv.y, tb);
        int j2 = __shfl(jv.z, tb), j3 = __shfl(jv.w, tb);
        if (j0 != i)           { cnt++; acc += states[j0 * D_DIM + lane]; }
        if (ct > 1 && j1 != i) { cnt++; acc += states[j1 * D_DIM + lane]; }
        if (ct > 2 && j2 != i) { cnt++; acc += states[j2 * D_DIM + lane]; }
        if (ct > 3 && j3 != i) { cnt++; acc += states[j3 * D_DIM + lane]; }
        if (ct > 4) {                                  // rare (P ~ 1e-6)
            int bb = __shfl(bin, tb) * BUCKET_CAP;
            for (int s = 4; s < ct; ++s) {
                int j = buckets[bb + s];
                if (j != i) { cnt++; acc += states[j * D_DIM + lane]; }
            }
        }
    }
    float nbr = (cnt > 0) ? acc / (float)cnt : 0.0f;

    __hip_bfloat16* row = xh + (size_t)i * 256;
    row[lane]       = __float2bfloat16(states[i * D_DIM + lane]);
    row[64 + lane]  = __float2bfloat16(nbr);
    row[128 + lane] = __float2bfloat16(h[i * H_DIM + lane]);
    row[192 + lane] = __float2bfloat16(h[i * H_DIM + 64 + lane]);
}

// ---------------- K4: mega — gate GEMM + LSTM + output heads, fully fused (r6 structure) ----
__global__ __launch_bounds__(512) void mega(const __hip_bfloat16* __restrict__ xh,
                                            const __hip_bfloat16* __restrict__ Wb,
                                            const float* __restrict__ bias,
                                            const float* __restrict__ c_in,
                                            const float* __restrict__ W_out,
                                            const float* __restrict__ W_role,
                                            float* __restrict__ out) {
    __shared__ char smem[69632];           // 68 KB
    char* As = smem;                       // GEMM: 32 rows x 128B
    char* Bs = smem + 4096;                // GEMM: 512 rows x 128B
    char* Hl   = smem;                     // epi: 32 x 256B bf16 h-tile
    char* Wohi = smem + 8192;              // epi: 64 x 256B
    char* Wolo = smem + 24576;             // epi: 64 x 256B
    char* Wr   = smem + 40960;             // epi: 16 x 256B (rows 3..15 zero)

    const int tid  = threadIdx.x;
    const int lane = tid & 63;
    const int wid  = tid >> 6;
    const int wrow = wid >> 2, wcol = wid & 3;
    const int n0 = blockIdx.x * 32;

    const char* aG = (const char*)xh;      // row stride 512B
    const char* bG = (const char*)Wb;      // row stride 512B

    f32x4 acc[8] = {};                     // [ni] over 128 cols of this wave

    for (int kc = 0; kc < 4; ++kc) {       // K = 256 in BK=64 chunks
        if (kc) __syncthreads();
        if (tid < 256) {                   // stage As: 256 x 16B
            int row = tid >> 3, slot = (tid & 7) << 4;
            __builtin_amdgcn_global_load_lds(
                (const __attribute__((address_space(1))) void*)(aG + (size_t)(n0 + row) * 512 + kc * 128 + (slot ^ ((row & 7) << 4))),
                (__attribute__((address_space(3))) void*)(As + row * 128 + slot), 16, 0, 0);
        }
        #pragma unroll
        for (int e = 0; e < 8; ++e) {      // stage Bs: 4096 x 16B
            int u = e * 512 + tid;
            int row = u >> 3, slot = (u & 7) << 4;
            __builtin_amdgcn_global_load_lds(
                (const __attribute__((address_space(1))) void*)(bG + (size_t)row * 512 + kc * 128 + (slot ^ ((row & 7) << 4))),
                (__attribute__((address_space(3))) void*)(Bs + row * 128 + slot), 16, 0, 0);
        }
        __syncthreads();

        #pragma unroll
        for (int ks = 0; ks < 2; ++ks) {
            int kb = ks * 64 + ((lane >> 4) << 4);
            int arow = wrow * 16 + (lane & 15);
            bf16x8 av = *(const bf16x8*)(As + arow * 128 + (kb ^ ((arow & 7) << 4)));
            #pragma unroll
            for (int ni = 0; ni < 8; ++ni) {
                int brow = wcol * 128 + ni * 16 + (lane & 15);
                bf16x8 bv = *(const bf16x8*)(Bs + brow * 128 + (kb ^ ((brow & 7) << 4)));
                acc[ni] = __builtin_amdgcn_mfma_f32_16x16x32_bf16(av, bv, acc[ni], 0, 0, 0);
            }
        }
    }
    __syncthreads();   // all GEMM LDS reads complete; repurpose LDS

    // ---- stage head weights: W_out split hi+lo bf16 (transposed to [d][h]), W_role [r][h] ----
    #pragma unroll
    for (int e = 0; e < 16; ++e) {
        int u = e * 512 + tid;             // u = h*64 + d over 8192
        int hh = u >> 6, d = u & 63;
        float w = W_out[u];
        float whi = __bfloat162float(__float2bfloat16(w));
        int off = d * 256 + ((hh * 2) ^ ((d & 7) << 4));
        *(short*)(Wohi + off) = f2bf(whi);
        *(short*)(Wolo + off) = f2bf(w - whi);
    }
    #pragma unroll
    for (int e = 0; e < 4; ++e) {
        int u = e * 512 + tid;             // 2048 slots: r(16) x h(128)
        int r = u >> 7, hh = u & 127;
        float w = (r < 3) ? W_role[hh * 3 + r] : 0.0f;
        *(short*)(Wr + r * 256 + ((hh * 2) ^ ((r & 7) << 4))) = f2bf(w);
    }

    // ---- LSTM pointwise in-register; h -> LDS (bf16, swizzled) ----
    #pragma unroll
    for (int b = 0; b < 2; ++b) {
        int hg = (2 * wcol + b) * 16 + (lane & 15);
        float bi = bias[hg], bff = bias[128 + hg], bgg = bias[256 + hg], boo = bias[384 + hg];
        #pragma unroll
        for (int r = 0; r < 4; ++r) {
            int ml = wrow * 16 + ((lane >> 4) << 2) + r;
            float ig = acc[b * 4 + 0][r] + bi;
            float fg = acc[b * 4 + 1][r] + bff;
            float gg = acc[b * 4 + 2][r] + bgg;
            float og = acc[b * 4 + 3][r] + boo;
            float cv = c_in[(size_t)(n0 + ml) * H_DIM + hg];
            float si = 1.0f / (1.0f + expf(-ig));
            float sf = 1.0f / (1.0f + expf(-fg));
            float so = 1.0f / (1.0f + expf(-og));
            float hn = so * tanhf(sf * cv + si * tanhf(gg));
            *(short*)(Hl + ml * 256 + ((hg * 2) ^ ((ml & 7) << 4))) = f2bf(hn);
        }
    }
    __syncthreads();

    // ---- head GEMMs: out = h @ W_out (hi+lo), roleT = Wr @ h^T ----
    const int rb = wid >> 2, db = wid & 3;
    f32x4 oacc = {};
    f32x4 racc = {};
    #pragma unroll
    for (int ks = 0; ks < 4; ++ks) {       // K = 128
        int kb = ks * 64 + ((lane >> 4) << 4);
        int hrow = rb * 16 + (lane & 15);
        bf16x8 hv = *(const bf16x8*)(Hl + hrow * 256 + (kb ^ ((hrow & 7) << 4)));
        int drow = db * 16 + (lane & 15);
        int woff = drow * 256 + (kb ^ ((drow & 7) << 4));
        bf16x8 whi = *(const bf16x8*)(Wohi + woff);
        bf16x8 wlo = *(const bf16x8*)(Wolo + woff);
        oacc = __builtin_amdgcn_mfma_f32_16x16x32_bf16(hv, whi, oacc, 0, 0, 0);
        oacc = __builtin_amdgcn_mfma_f32_16x16x32_bf16(hv, wlo, oacc, 0, 0, 0);
        if (db == 3) {
            int rrow = lane & 15;
            bf16x8 wr = *(const bf16x8*)(Wr + rrow * 256 + (kb ^ ((rrow & 7) << 4)));
            racc = __builtin_amdgcn_mfma_f32_16x16x32_bf16(wr, hv, racc, 0, 0, 0);
        }
    }
    #pragma unroll
    for (int r = 0; r < 4; ++r) {
        int m = n0 + rb * 16 + ((lane >> 4) << 2) + r;
        out[(size_t)m * D_DIM + db * 16 + (lane & 15)] = oacc[r];
    }
    if (db == 3 && lane < 16) {
        int m = n0 + rb * 16 + lane;
        float l0 = racc[0], l1 = racc[1], l2 = racc[2];
        float mx = fmaxf(l0, fmaxf(l1, l2));
        float e0 = expf(l0 - mx), e1 = expf(l1 - mx), e2 = expf(l2 - mx);
        float s = e0 + e1 + e2;
        float* ro = out + (size_t)N_CELLS * D_DIM + (size_t)m * 3;
        ro[0] = e0 / s; ro[1] = e1 / s; ro[2] = e2 / s;
    }
}

// ---------------- host launcher ----------------
extern "C" void kernel_launch(void* const* d_in, const int* in_sizes, int n_in,
                              void* d_out, int out_size, void* d_ws, size_t ws_size,
                              hipStream_t stream) {
    const int*   positions = (const int*)d_in[0];
    const float* states    = (const float*)d_in[1];
    const float* h         = (const float*)d_in[2];
    const float* c         = (const float*)d_in[3];
    const float* Wih       = (const float*)d_in[4];
    const float* Whh       = (const float*)d_in[5];
    const float* bias      = (const float*)d_in[6];
    const float* Wout      = (const float*)d_in[7];
    const float* Wrole     = (const float*)d_in[8];
    float* out             = (float*)d_out;

    char* ws = (char*)d_ws;
    int*            counts  = (int*)ws;                         // 256 KB @ 0
    int*            buckets = (int*)(ws + 262144);              // 4 MB
    __hip_bfloat16* xh      = (__hip_bfloat16*)(ws + 4456448);  // 4 MB   [8192,256] bf16
    __hip_bfloat16* Wb      = (__hip_bfloat16*)(ws + 8650752);  // 256 KB [512,256] bf16

    prep<<<192, 256, 0, stream>>>(Wih, Whh, Wb, (int4*)counts);
    bin_fill<<<N_CELLS / 256, 256, 0, stream>>>(positions, counts, buckets);
    build_xh<<<N_CELLS / 4, 256, 0, stream>>>(positions, states, h, counts, buckets, xh);
    mega<<<N_CELLS / 32, 512, 0, stream>>>(xh, Wb, bias, c, Wout, Wrole, out);
}

// Round 10
// 33.607 us; speedup vs baseline: 1.3061x; 1.0293x over previous
//
#include <hip/hip_runtime.h>
#include <hip/hip_bf16.h>
#include <math.h>

#define N_CELLS 8192
#define D_DIM 64
#define H_DIM 128
#define GRID_SZ 256
#define NBINS (GRID_SZ * GRID_SZ)
#define BUCKET_CAP 16

typedef short bf16x8 __attribute__((ext_vector_type(8)));
typedef float f32x4 __attribute__((ext_vector_type(4)));

static __device__ __forceinline__ short f2bf(float x) {
    __hip_bfloat16 b = __float2bfloat16(x);
    return __builtin_bit_cast(short, b);
}

// ---------------- K1: prep — Wb pack (0..127) | clear counts (128..191) |
//                  W_out hi/lo pack transposed (192..223) | W_role pad (224) ----------------
__global__ __launch_bounds__(256) void prep(const float* __restrict__ Wih,
                                            const float* __restrict__ Whh,
                                            const float* __restrict__ W_out,
                                            const float* __restrict__ W_role,
                                            __hip_bfloat16* __restrict__ Wb,
                                            __hip_bfloat16* __restrict__ Wohi,
                                            __hip_bfloat16* __restrict__ Wolo,
                                            __hip_bfloat16* __restrict__ Wr,
                                            int4* __restrict__ counts4) {
    int tid = threadIdx.x, b = blockIdx.x;
    if (b < 128) {
        // Wb row g': group=g'>>6, c6=g'&63, gate=c6>>4, hl=c6&15; orig = gate*128+group*16+hl
        int idx4 = b * 256 + tid;   // 32768 float4 chunks
        int gp = idx4 >> 6, k4 = (idx4 & 63) << 2;
        int group = gp >> 6, c6 = gp & 63, gate = c6 >> 4, hl = c6 & 15;
        int orig = gate * 128 + group * 16 + hl;
        float4 v = (k4 < 128) ? *(const float4*)(Wih + orig * 128 + k4)
                              : *(const float4*)(Whh + orig * 128 + (k4 - 128));
        short4 o = make_short4(f2bf(v.x), f2bf(v.y), f2bf(v.z), f2bf(v.w));
        *(short4*)((short*)Wb + gp * 256 + k4) = o;
    } else if (b < 192) {
        counts4[(b - 128) * 256 + tid] = make_int4(0, 0, 0, 0);
    } else if (b < 224) {
        int u = (b - 192) * 256 + tid;       // 8192: u = h*64 + d
        int hh = u >> 6, d = u & 63;
        float w = W_out[u];
        float whi = __bfloat162float(__float2bfloat16(w));
        Wohi[d * 128 + hh] = __float2bfloat16(whi);
        Wolo[d * 128 + hh] = __float2bfloat16(w - whi);
    } else {
        #pragma unroll
        for (int e = 0; e < 8; ++e) {        // 2048: r(16) x h(128), rows 3..15 zero
            int u = e * 256 + tid;
            int r = u >> 7, hh = u & 127;
            float w = (r < 3) ? W_role[hh * 3 + r] : 0.0f;
            Wr[r * 128 + hh] = __float2bfloat16(w);
        }
    }
}

// ---------------- K2: fill spatial-hash buckets ----------------
__global__ __launch_bounds__(256) void bin_fill(const int* __restrict__ positions,
                                                int* __restrict__ counts,
                                                int* __restrict__ buckets) {
    int i = blockIdx.x * 256 + threadIdx.x;
    if (i >= N_CELLS) return;
    int p0 = positions[2 * i], p1 = positions[2 * i + 1];
    int bin = p0 * GRID_SZ + p1;
    int slot = atomicAdd(&counts[bin], 1);
    if (slot < BUCKET_CAP) buckets[bin * BUCKET_CAP + slot] = i;
}

// ---------------- K3: build_xh — WAVE-PARALLEL gather (lane t probes stencil bin t) ----------
__global__ __launch_bounds__(256) void build_xh(const int* __restrict__ positions,
                                                const float* __restrict__ states,
                                                const float* __restrict__ h,
                                                const int* __restrict__ counts,
                                                const int* __restrict__ buckets,
                                                __hip_bfloat16* __restrict__ xh) {
    int wave = threadIdx.x >> 6;
    int lane = threadIdx.x & 63;
    int i = blockIdx.x * 4 + wave;   // one wave per cell
    int p0 = positions[2 * i], p1 = positions[2 * i + 1];

    // lane t -> stencil offset (da,db), t in [0,29)
    int t = lane;
    int da, db;
    if (t == 0)      { da = -3; db = 0; }
    else if (t < 6)  { da = -2; db = t - 3; }
    else if (t < 11) { da = -1; db = t - 8; }
    else if (t < 18) { da = 0;  db = t - 14; }
    else if (t < 23) { da = 1;  db = t - 20; }
    else if (t < 28) { da = 2;  db = t - 25; }
    else             { da = 3;  db = 0; }

    int q0 = p0 + da, q1 = p1 + db;
    bool ok = (lane < 29) && ((unsigned)q0 < GRID_SZ) && ((unsigned)q1 < GRID_SZ);
    int bin = q0 * GRID_SZ + q1;

    int cl = 0;
    int4 jv = make_int4(0, 0, 0, 0);
    if (ok) {
        cl = counts[bin];                                 // parallel across lanes
        jv = *(const int4*)(buckets + bin * BUCKET_CAP);  // independent -> same latency wave
        if (cl > BUCKET_CAP) cl = BUCKET_CAP;
    }

    unsigned long long act = __ballot(cl > 0);
    float acc = 0.0f;
    int cnt = 0;
    while (act) {
        int tb = __ffsll(act) - 1;
        act &= act - 1;
        int ct = __shfl(cl, tb);
        int j0 = __shfl(jv.x, tb), j1 = __shfl(jv.y, tb);
        int j2 = __shfl(jv.z, tb), j3 = __shfl(jv.w, tb);
        if (j0 != i)           { cnt++; acc += states[j0 * D_DIM + lane]; }
        if (ct > 1 && j1 != i) { cnt++; acc += states[j1 * D_DIM + lane]; }
        if (ct > 2 && j2 != i) { cnt++; acc += states[j2 * D_DIM + lane]; }
        if (ct > 3 && j3 != i) { cnt++; acc += states[j3 * D_DIM + lane]; }
        if (ct > 4) {                                      // rare (P ~ 1e-6)
            int bb = __shfl(bin, tb) * BUCKET_CAP;
            for (int s = 4; s < ct; ++s) {
                int j = buckets[bb + s];
                if (j != i) { cnt++; acc += states[j * D_DIM + lane]; }
            }
        }
    }
    float nbr = (cnt > 0) ? acc / (float)cnt : 0.0f;

    __hip_bfloat16* row = xh + (size_t)i * 256;
    row[lane]       = __float2bfloat16(states[i * D_DIM + lane]);
    row[64 + lane]  = __float2bfloat16(nbr);
    row[128 + lane] = __float2bfloat16(h[i * H_DIM + lane]);
    row[192 + lane] = __float2bfloat16(h[i * H_DIM + 64 + lane]);
}

// ---------------- K4: mega — gate GEMM + LSTM + heads; W-head staging + c_in hoisted ----------
// LDS regions coexist (112 KB): no repurposing, W staging issued at start hides under GEMM.
__global__ __launch_bounds__(512) void mega(const __hip_bfloat16* __restrict__ xh,
                                            const __hip_bfloat16* __restrict__ Wb,
                                            const float* __restrict__ bias,
                                            const float* __restrict__ c_in,
                                            const __hip_bfloat16* __restrict__ Wohi,
                                            const __hip_bfloat16* __restrict__ Wolo,
                                            const __hip_bfloat16* __restrict__ Wr,
                                            float* __restrict__ out) {
    __shared__ char smem[114688];          // 112 KB
    char* As  = smem;                      // 32 x 128B per kc chunk
    char* Bs  = smem + 4096;               // 512 x 128B per kc chunk
    char* Whi = smem + 69632;              // 64 x 256B
    char* Wlo = smem + 86016;              // 64 x 256B
    char* Wrl = smem + 102400;             // 16 x 256B
    char* Hl  = smem + 106496;             // 32 x 256B

    const int tid  = threadIdx.x;
    const int lane = tid & 63;
    const int wid  = tid >> 6;
    const int wrow = wid >> 2, wcol = wid & 3;
    const int n0 = blockIdx.x * 32;

    // ---- issue head-weight staging first: latency hides under the GEMM K-loop ----
    const char* hiG = (const char*)Wohi;   // [64][128] bf16, row 256B
    const char* loG = (const char*)Wolo;
    const char* wrG = (const char*)Wr;     // [16][128] bf16
    #pragma unroll
    for (int e = 0; e < 2; ++e) {          // 1024 granules each
        int u = e * 512 + tid;
        int row = u >> 4, slot = (u & 15) << 4;
        int src = row * 256 + (slot ^ ((row & 7) << 4));
        __builtin_amdgcn_global_load_lds(
            (const __attribute__((address_space(1))) void*)(hiG + src),
            (__attribute__((address_space(3))) void*)(Whi + row * 256 + slot), 16, 0, 0);
        __builtin_amdgcn_global_load_lds(
            (const __attribute__((address_space(1))) void*)(loG + src),
            (__attribute__((address_space(3))) void*)(Wlo + row * 256 + slot), 16, 0, 0);
    }
    if (tid < 256) {                       // Wr: 256 granules
        int row = tid >> 4, slot = (tid & 15) << 4;
        __builtin_amdgcn_global_load_lds(
            (const __attribute__((address_space(1))) void*)(wrG + row * 256 + (slot ^ ((row & 7) << 4))),
            (__attribute__((address_space(3))) void*)(Wrl + row * 256 + slot), 16, 0, 0);
    }

    // ---- c_in prefetch into registers (consumed after GEMM) ----
    float cv[2][4];
    #pragma unroll
    for (int b = 0; b < 2; ++b) {
        int hg = (2 * wcol + b) * 16 + (lane & 15);
        #pragma unroll
        for (int r = 0; r < 4; ++r) {
            int ml = wrow * 16 + ((lane >> 4) << 2) + r;
            cv[b][r] = c_in[(size_t)(n0 + ml) * H_DIM + hg];
        }
    }

    const char* aG = (const char*)xh;      // row stride 512B
    const char* bG = (const char*)Wb;      // row stride 512B

    f32x4 acc[8] = {};                     // [ni] over 128 cols of this wave

    for (int kc = 0; kc < 4; ++kc) {       // K = 256 in BK=64 chunks
        if (kc) __syncthreads();
        if (tid < 256) {                   // stage As: 256 x 16B
            int row = tid >> 3, slot = (tid & 7) << 4;
            __builtin_amdgcn_global_load_lds(
                (const __attribute__((address_space(1))) void*)(aG + (size_t)(n0 + row) * 512 + kc * 128 + (slot ^ ((row & 7) << 4))),
                (__attribute__((address_space(3))) void*)(As + row * 128 + slot), 16, 0, 0);
        }
        #pragma unroll
        for (int e = 0; e < 8; ++e) {      // stage Bs: 4096 x 16B
            int u = e * 512 + tid;
            int row = u >> 3, slot = (u & 7) << 4;
            __builtin_amdgcn_global_load_lds(
                (const __attribute__((address_space(1))) void*)(bG + (size_t)row * 512 + kc * 128 + (slot ^ ((row & 7) << 4))),
                (__attribute__((address_space(3))) void*)(Bs + row * 128 + slot), 16, 0, 0);
        }
        __syncthreads();

        #pragma unroll
        for (int ks = 0; ks < 2; ++ks) {
            int kb = ks * 64 + ((lane >> 4) << 4);
            int arow = wrow * 16 + (lane & 15);
            bf16x8 av = *(const bf16x8*)(As + arow * 128 + (kb ^ ((arow & 7) << 4)));
            #pragma unroll
            for (int ni = 0; ni < 8; ++ni) {
                int brow = wcol * 128 + ni * 16 + (lane & 15);
                bf16x8 bv = *(const bf16x8*)(Bs + brow * 128 + (kb ^ ((brow & 7) << 4)));
                acc[ni] = __builtin_amdgcn_mfma_f32_16x16x32_bf16(av, bv, acc[ni], 0, 0, 0);
            }
        }
    }

    // ---- LSTM pointwise in-register (c_in already in regs); h -> LDS (bf16, swizzled) ----
    #pragma unroll
    for (int b = 0; b < 2; ++b) {
        int hg = (2 * wcol + b) * 16 + (lane & 15);
        float bi = bias[hg], bff = bias[128 + hg], bgg = bias[256 + hg], boo = bias[384 + hg];
        #pragma unroll
        for (int r = 0; r < 4; ++r) {
            int ml = wrow * 16 + ((lane >> 4) << 2) + r;
            float ig = acc[b * 4 + 0][r] + bi;
            float fg = acc[b * 4 + 1][r] + bff;
            float gg = acc[b * 4 + 2][r] + bgg;
            float og = acc[b * 4 + 3][r] + boo;
            float si = 1.0f / (1.0f + expf(-ig));
            float sf = 1.0f / (1.0f + expf(-fg));
            float so = 1.0f / (1.0f + expf(-og));
            float hn = so * tanhf(sf * cv[b][r] + si * tanhf(gg));
            *(short*)(Hl + ml * 256 + ((hg * 2) ^ ((ml & 7) << 4))) = f2bf(hn);
        }
    }
    __syncthreads();

    // ---- head GEMMs: out = h @ W_out (hi+lo), roleT = Wr @ h^T ----
    const int rb = wid >> 2, db = wid & 3;
    f32x4 oacc = {};
    f32x4 racc = {};
    #pragma unroll
    for (int ks = 0; ks < 4; ++ks) {       // K = 128
        int kb = ks * 64 + ((lane >> 4) << 4);
        int hrow = rb * 16 + (lane & 15);
        bf16x8 hv = *(const bf16x8*)(Hl + hrow * 256 + (kb ^ ((hrow & 7) << 4)));
        int drow = db * 16 + (lane & 15);
        int woff = drow * 256 + (kb ^ ((drow & 7) << 4));
        bf16x8 whi = *(const bf16x8*)(Whi + woff);
        bf16x8 wlo = *(const bf16x8*)(Wlo + woff);
        oacc = __builtin_amdgcn_mfma_f32_16x16x32_bf16(hv, whi, oacc, 0, 0, 0);
        oacc = __builtin_amdgcn_mfma_f32_16x16x32_bf16(hv, wlo, oacc, 0, 0, 0);
        if (db == 3) {
            int rrow = lane & 15;
            bf16x8 wr = *(const bf16x8*)(Wrl + rrow * 256 + (kb ^ ((rrow & 7) << 4)));
            racc = __builtin_amdgcn_mfma_f32_16x16x32_bf16(wr, hv, racc, 0, 0, 0);
        }
    }
    #pragma unroll
    for (int r = 0; r < 4; ++r) {
        int m = n0 + rb * 16 + ((lane >> 4) << 2) + r;
        out[(size_t)m * D_DIM + db * 16 + (lane & 15)] = oacc[r];
    }
    if (db == 3 && lane < 16) {
        int m = n0 + rb * 16 + lane;
        float l0 = racc[0], l1 = racc[1], l2 = racc[2];
        float mx = fmaxf(l0, fmaxf(l1, l2));
        float e0 = expf(l0 - mx), e1 = expf(l1 - mx), e2 = expf(l2 - mx);
        float s = e0 + e1 + e2;
        float* ro = out + (size_t)N_CELLS * D_DIM + (size_t)m * 3;
        ro[0] = e0 / s; ro[1] = e1 / s; ro[2] = e2 / s;
    }
}

// ---------------- host launcher ----------------
extern "C" void kernel_launch(void* const* d_in, const int* in_sizes, int n_in,
                              void* d_out, int out_size, void* d_ws, size_t ws_size,
                              hipStream_t stream) {
    const int*   positions = (const int*)d_in[0];
    const float* states    = (const float*)d_in[1];
    const float* h         = (const float*)d_in[2];
    const float* c         = (const float*)d_in[3];
    const float* Wih       = (const float*)d_in[4];
    const float* Whh       = (const float*)d_in[5];
    const float* bias      = (const float*)d_in[6];
    const float* Wout      = (const float*)d_in[7];
    const float* Wrole     = (const float*)d_in[8];
    float* out             = (float*)d_out;

    char* ws = (char*)d_ws;
    int*            counts  = (int*)ws;                          // 256 KB @ 0
    int*            buckets = (int*)(ws + 262144);               // 4 MB
    __hip_bfloat16* xh      = (__hip_bfloat16*)(ws + 4456448);   // 4 MB   [8192,256] bf16
    __hip_bfloat16* Wb      = (__hip_bfloat16*)(ws + 8650752);   // 256 KB [512,256] bf16
    __hip_bfloat16* Wohi    = (__hip_bfloat16*)(ws + 8912896);   // 16 KB  [64,128] bf16
    __hip_bfloat16* Wolo    = (__hip_bfloat16*)(ws + 8929280);   // 16 KB
    __hip_bfloat16* Wr      = (__hip_bfloat16*)(ws + 8945664);   // 4 KB   [16,128] bf16

    prep<<<225, 256, 0, stream>>>(Wih, Whh, Wout, Wrole, Wb, Wohi, Wolo, Wr, (int4*)counts);
    bin_fill<<<N_CELLS / 256, 256, 0, stream>>>(positions, counts, buckets);
    build_xh<<<N_CELLS / 4, 256, 0, stream>>>(positions, states, h, counts, buckets, xh);
    mega<<<N_CELLS / 32, 512, 0, stream>>>(xh, Wb, bias, c, Wohi, Wolo, Wr, out);
}